// Round 12
// baseline (373.862 us; speedup 1.0000x reference)
//
#include <hip/hip_runtime.h>
#include <cstdint>
#include <cstddef>

// ---------------------------------------------------------------------------
// 2-layer GAT on MI355X — fp8 value rows both layers, fused dispatch graph,
// channel-split agg1 (2 blocks/node x 4 edge-streams = 8 gathers in flight).
//   memset(deg+flag) ; pack2(W1+W2 + detect block)
//   mega1: [gemm1: h1q(fp8)=x@W1 + fused als/ald] || [extract blocks]
//   scan_a ; scan_c(inline bsum scan) ; fill
//   agg1 grid.y=2: fp8 half-row gather (128B), 16 lanes/edge, 4 streams
//   gemm2: h2q(fp8 128B rows) = hactb @ W2 + fused als/ald
//   agg2 (fp8 128B = 1 line/row, 16 lanes/edge, 4 streams) -> log_softmax out
// ---------------------------------------------------------------------------

typedef short bf16x8 __attribute__((ext_vector_type(8)));
typedef unsigned short u16x8 __attribute__((ext_vector_type(8)));
typedef float f32x4 __attribute__((ext_vector_type(4)));

__device__ inline unsigned short f2bf(float f) {
  unsigned u = __float_as_uint(f);
  unsigned r = (u + 0x7FFFu + ((u >> 16) & 1u)) >> 16;  // RNE
  return (unsigned short)r;
}
__device__ inline float bf2f(unsigned short s) {
  return __uint_as_float((unsigned)s << 16);
}

// ---- OCP e4m3fn helpers ---------------------------------------------------
__device__ inline unsigned char fp8enc(float x) {
  unsigned u = __float_as_uint(x);
  unsigned s = u >> 31;
  float ax = fminf(fabsf(x), 448.f);
  unsigned em;
  if (ax >= 0.015625f) {  // normal
    unsigned b = __float_as_uint(ax);
    unsigned b2 = b + 0x7FFFFu + ((b >> 20) & 1u);  // RNE to 3 mantissa bits
    em = (b2 >> 20) - 960u;
    if (em > 126u) em = 126u;  // clamp to 448
  } else {                     // denormal: m * 2^-9
    em = (unsigned)__float2int_rn(ax * 512.f);
  }
  return (unsigned char)((s << 7) | em);
}
__device__ inline float fp8dec_sw(unsigned b8) {
  unsigned s = b8 >> 7, em = b8 & 0x7Fu;
  float fn = __uint_as_float((s << 31) | ((em + 960u) << 20));
  float fd = (float)em * 0.001953125f;
  fd = s ? -fd : fd;
  return em >= 8u ? fn : fd;
}
__device__ inline void fp8dec4(unsigned w, float* out) {
#if __has_builtin(__builtin_amdgcn_cvt_f32_fp8)
  out[0] = __builtin_amdgcn_cvt_f32_fp8(w, 0);
  out[1] = __builtin_amdgcn_cvt_f32_fp8(w, 1);
  out[2] = __builtin_amdgcn_cvt_f32_fp8(w, 2);
  out[3] = __builtin_amdgcn_cvt_f32_fp8(w, 3);
#else
  out[0] = fp8dec_sw(w & 0xFFu);
  out[1] = fp8dec_sw((w >> 8) & 0xFFu);
  out[2] = fp8dec_sw((w >> 16) & 0xFFu);
  out[3] = fp8dec_sw((w >> 24) & 0xFFu);
#endif
}

// ------------------------------- CSR build ---------------------------------

__global__ __launch_bounds__(256) void scan_a(const int* __restrict__ deg,
                                              int* __restrict__ off,
                                              int* __restrict__ bsum, int N) {
  __shared__ int sh[256];
  int b = blockIdx.x, t = threadIdx.x;
  int base = b * 2048 + t * 8;
  int p[8];
  int run = 0;
#pragma unroll
  for (int j = 0; j < 8; ++j) {
    int v = (base + j < N) ? deg[base + j] : 0;
    run += v;
    p[j] = run;
  }
  sh[t] = run;
  __syncthreads();
  for (int d = 1; d < 256; d <<= 1) {
    int x = (t >= d) ? sh[t - d] : 0;
    __syncthreads();
    if (t >= d) sh[t] += x;
    __syncthreads();
  }
  int excl = sh[t] - run;
#pragma unroll
  for (int j = 0; j < 8; ++j)
    if (base + j < N) off[base + j + 1] = excl + p[j];
  if (t == 255) bsum[b] = sh[255];
}

// scan_c with inlined bsum scan; nb <= 64
__global__ __launch_bounds__(256) void scan_c(int* __restrict__ off,
                                              const int* __restrict__ bsum,
                                              int N, int nb) {
  __shared__ int sb[64];
  int t = threadIdx.x;
  if (t < 64) {
    int v = (t < nb) ? bsum[t] : 0;
    for (int d = 1; d < 64; d <<= 1) {
      int u = __shfl_up(v, d);
      if (t >= d) v += u;
    }
    sb[t] = v;  // inclusive scan
  }
  __syncthreads();
  int i = blockIdx.x * 256 + t;
  if (i == 0) off[0] = 0;
  if (i >= 1 && i <= N) {
    int c = (i - 1) / 2048;
    int excl = (c == 0) ? 0 : sb[c - 1];
    off[i] += excl;
  }
}

__global__ __launch_bounds__(256) void fill_kernel(const int* __restrict__ src,
                                                   const int* __restrict__ dst,
                                                   const int* __restrict__ off,
                                                   int* __restrict__ deg,
                                                   int* __restrict__ csr, int ET) {
  int e = blockIdx.x * 256 + threadIdx.x;
  if (e >= ET) return;
  int d = dst[e];
  int p = atomicSub(&deg[d], 1) - 1;
  csr[off[d] + p] = src[e];
}

// ------------------- weight pre-pack + int-width detect --------------------
__device__ inline void pack_one(const float* __restrict__ W,
                                short* __restrict__ Wp, int NOUT, int idx) {
  int NT = NOUT >> 4;
  int j = idx & 7;
  int lane = (idx >> 3) & 63;
  int st = idx >> 9;
  int s = st / NT, t = st - s * NT;
  int k = s * 32 + (lane >> 4) * 8 + j;
  int n = t * 16 + (lane & 15);
  Wp[idx] = (short)f2bf(W[(size_t)k * NOUT + n]);
}

__global__ __launch_bounds__(256) void pack2_kernel(const float* __restrict__ W1,
                                                    short* __restrict__ W1p,
                                                    const float* __restrict__ W2,
                                                    short* __restrict__ W2p,
                                                    const int* __restrict__ words,
                                                    int E, int* __restrict__ flag) {
  int b = blockIdx.x, t = threadIdx.x;
  if (b < 128) {
    pack_one(W1, W1p, 256, b * 256 + t);          // 128*256 elems
  } else if (b < 256) {
    pack_one(W2, W2p, 128, (b - 128) * 256 + t);  // 256*128 elems
  } else {                                        // detect block
    int n = E < 1024 ? E : 1024;
    int cnt = 0;
    for (int i = t; i < n; i += 256) cnt += (words[2 * i + 1] != 0) ? 1 : 0;
    for (int m = 1; m < 64; m <<= 1) cnt += __shfl_xor(cnt, m);
    if ((t & 63) == 0 && cnt) atomicAdd(flag, cnt);
  }
}

// ------------------------------ MFMA GEMM body -----------------------------
template <int K, int NOUT, bool AF32>
__device__ void gemm_body(int bx, const void* __restrict__ Av,
                          const short* __restrict__ Bp,
                          unsigned char* __restrict__ Cq,
                          const float* __restrict__ as,
                          const float* __restrict__ ad,
                          float* __restrict__ alsO,
                          float* __restrict__ aldO, int M) {
  constexpr int KS = K / 32;
  constexpr int NT = NOUT / 16;
  constexpr int RST = NOUT + 8;   // bf16 LDS row stride (shorts)
  constexpr int QST = NOUT + 16;  // fp8 LDS row stride (bytes)
  constexpr int C = NOUT / 8;     // channels per head
  __shared__ __align__(16) short lds[64 * RST];
  __shared__ __align__(16) unsigned char ldsq[64 * QST];
  const int tid = threadIdx.x;
  const int wave = tid >> 6, lane = tid & 63;
  const int lo = lane & 15, hi = lane >> 4;
  const int rowA = bx * 64 + wave * 16 + lo;
  const bool inb = rowA < M;

  f32x4 acc[NT];
#pragma unroll
  for (int t = 0; t < NT; ++t) acc[t] = (f32x4){0.f, 0.f, 0.f, 0.f};

#pragma unroll
  for (int s = 0; s < KS; ++s) {
    bf16x8 af;
    if constexpr (AF32) {
      const float* Ap = (const float*)Av;
      float v[8];
      if (inb) {
        const float4 x0 = *(const float4*)&Ap[(size_t)rowA * K + s * 32 + hi * 8];
        const float4 x1 = *(const float4*)&Ap[(size_t)rowA * K + s * 32 + hi * 8 + 4];
        v[0] = x0.x; v[1] = x0.y; v[2] = x0.z; v[3] = x0.w;
        v[4] = x1.x; v[5] = x1.y; v[6] = x1.z; v[7] = x1.w;
      } else {
#pragma unroll
        for (int j = 0; j < 8; ++j) v[j] = 0.f;
      }
#pragma unroll
      for (int j = 0; j < 8; ++j) af[j] = (short)f2bf(v[j]);
    } else {
      const short* Ab = (const short*)Av;
      if (inb) {
        af = *(const bf16x8*)&Ab[(size_t)rowA * K + s * 32 + hi * 8];
      } else {
#pragma unroll
        for (int j = 0; j < 8; ++j) af[j] = 0;
      }
    }
#pragma unroll
    for (int t = 0; t < NT; ++t) {
      bf16x8 bf = *(const bf16x8*)&Bp[((size_t)(s * NT + t) * 64 + lane) * 8];
      acc[t] = __builtin_amdgcn_mfma_f32_16x16x32_bf16(af, bf, acc[t], 0, 0, 0);
    }
  }

#pragma unroll
  for (int t = 0; t < NT; ++t)
#pragma unroll
    for (int r = 0; r < 4; ++r) {
      int row = wave * 16 + hi * 4 + r;
      lds[row * RST + t * 16 + lo] = (short)f2bf(acc[t][r]);
      ldsq[row * QST + t * 16 + lo] = fp8enc(acc[t][r]);
    }
  __syncthreads();

  // coalesced fp8 store
  constexpr int CPR = NOUT / 16;  // 16B chunks per row
#pragma unroll
  for (int i = 0; i < (64 * CPR) / 256; ++i) {
    int v = i * 256 + tid;
    int r = v / CPR;
    int c = v % CPR;
    int grow = bx * 64 + r;
    if (grow < M)
      *(float4*)&Cq[(size_t)grow * NOUT + c * 16] =
          *(const float4*)&ldsq[r * QST + c * 16];
  }

  // fused al epilogue (bf16 LDS tile — logits stay full precision)
  constexpr int SEGS = NOUT / 64;
  if (tid < 64 * SEGS) {
    int r = tid / SEGS, seg = tid % SEGS;
    int grow = bx * 64 + r;
    float ps[8], pd[8];
#pragma unroll
    for (int k = 0; k < 8; ++k) { ps[k] = 0.f; pd[k] = 0.f; }
#pragma unroll
    for (int k = 0; k < 8; ++k) {
      int b = seg + SEGS * k;
      u16x8 u = *(const u16x8*)&lds[r * RST + b * 8];
#pragma unroll
      for (int j = 0; j < 8; ++j) {
        float hv = bf2f(u[j]);
        ps[k] = fmaf(hv, as[k * C + seg * 8 + j], ps[k]);
        pd[k] = fmaf(hv, ad[k * C + seg * 8 + j], pd[k]);
      }
    }
#pragma unroll
    for (int d = 1; d < SEGS; d <<= 1)
#pragma unroll
      for (int k = 0; k < 8; ++k) {
        ps[k] += __shfl_xor(ps[k], d);
        pd[k] += __shfl_xor(pd[k], d);
      }
    if (seg == 0 && grow < M) {
      *(float4*)&alsO[(size_t)grow * 8] = make_float4(ps[0], ps[1], ps[2], ps[3]);
      *(float4*)&alsO[(size_t)grow * 8 + 4] = make_float4(ps[4], ps[5], ps[6], ps[7]);
      *(float4*)&aldO[(size_t)grow * 8] = make_float4(pd[0], pd[1], pd[2], pd[3]);
      *(float4*)&aldO[(size_t)grow * 8 + 4] = make_float4(pd[4], pd[5], pd[6], pd[7]);
    }
  }
}

// mega1: gemm1 blocks || extract blocks
__global__ __launch_bounds__(256) void mega1_kernel(
    const float* __restrict__ x, const short* __restrict__ W1p,
    unsigned char* __restrict__ h1q, const float* __restrict__ as1,
    const float* __restrict__ ad1, float* __restrict__ als,
    float* __restrict__ ald, int M, int gemmGrid,
    const void* __restrict__ ei, int E, int N, const int* __restrict__ flag,
    int* __restrict__ src, int* __restrict__ dst, int* __restrict__ deg) {
  int bx = blockIdx.x;
  if (bx < gemmGrid) {
    gemm_body<128, 256, true>(bx, x, W1p, h1q, as1, ad1, als, ald, M);
  } else {
    int e = (bx - gemmGrid) * 256 + threadIdx.x;
    int ET = E + N;
    if (e >= ET) return;
    int s, d;
    if (e < E) {
      if (flag[0] == 0) {  // int64
        const long long* p = (const long long*)ei;
        s = (int)p[e];
        d = (int)p[(size_t)E + e];
      } else {             // int32
        const int* p = (const int*)ei;
        s = p[e];
        d = p[E + e];
      }
    } else {
      s = d = e - E;  // self loop
    }
    src[e] = s;
    dst[e] = d;
    atomicAdd(&deg[d], 1);
  }
}

template <int K, int NOUT, bool AF32>
__global__ __launch_bounds__(256) void mfma_gemm(const void* __restrict__ Av,
                                                 const short* __restrict__ Bp,
                                                 unsigned char* __restrict__ Cq,
                                                 const float* __restrict__ as,
                                                 const float* __restrict__ ad,
                                                 float* __restrict__ alsO,
                                                 float* __restrict__ aldO, int M) {
  gemm_body<K, NOUT, AF32>(blockIdx.x, Av, Bp, Cq, as, ad, alsO, aldO, M);
}

// ------------- layer-1 aggregation (fp8, channel-split, 4 streams) ---------
// grid.y=2: each block-half covers 128B of the 256B row. 16 lanes/edge x 8B,
// 4 edge streams, 2x unroll. 8 row-gathers in flight per node total.
__global__ __launch_bounds__(256) void agg1_kernel(const unsigned char* __restrict__ hq,
                                                   const float* __restrict__ als,
                                                   const float* __restrict__ ald,
                                                   const int* __restrict__ off,
                                                   const int* __restrict__ csr,
                                                   const float* __restrict__ bias,
                                                   short* __restrict__ outb, int N) {
  int wid = blockIdx.x * 4 + (threadIdx.x >> 6);
  if (wid >= N) return;
  int cb = blockIdx.y;        // channel half (0..1)
  int lane = threadIdx.x & 63;
  int rs = off[wid], re = off[wid + 1];
  int es = lane >> 4;         // 4 edge streams
  int gl = lane & 15;         // 8 channels each
  int chb = cb * 128 + gl * 8;  // channel base
  int head = chb >> 5;          // 32 ch/head
  float aldv = ald[wid * 8 + head];

  float acc[8];
#pragma unroll
  for (int j = 0; j < 8; ++j) acc[j] = 0.f;
  float ws = 0.f;

  int i = rs + es;
  for (; i + 4 < re; i += 8) {
    int s0 = csr[i], s1 = csr[i + 4];
    float a0 = als[s0 * 8 + head];
    float a1 = als[s1 * 8 + head];
    uint2 u0 = *(const uint2*)&hq[(size_t)s0 * 256 + chb];
    uint2 u1 = *(const uint2*)&hq[(size_t)s1 * 256 + chb];
    float e0 = a0 + aldv, e1 = a1 + aldv;
    e0 = fmaxf(e0, 0.2f * e0);
    e1 = fmaxf(e1, 0.2f * e1);
    float w0 = __expf(e0), w1 = __expf(e1);
    ws += w0 + w1;
    float d0[8], d1[8];
    fp8dec4(u0.x, d0); fp8dec4(u0.y, d0 + 4);
    fp8dec4(u1.x, d1); fp8dec4(u1.y, d1 + 4);
#pragma unroll
    for (int j = 0; j < 8; ++j)
      acc[j] = fmaf(w1, d1[j], fmaf(w0, d0[j], acc[j]));
  }
  if (i < re) {
    int s0 = csr[i];
    float e0 = als[s0 * 8 + head] + aldv;
    uint2 u0 = *(const uint2*)&hq[(size_t)s0 * 256 + chb];
    e0 = fmaxf(e0, 0.2f * e0);
    float w0 = __expf(e0);
    ws += w0;
    float d0[8];
    fp8dec4(u0.x, d0); fp8dec4(u0.y, d0 + 4);
#pragma unroll
    for (int j = 0; j < 8; ++j) acc[j] = fmaf(w0, d0[j], acc[j]);
  }

  // combine 4 edge streams
#pragma unroll
  for (int d = 16; d < 64; d <<= 1) {
    ws += __shfl_xor(ws, d);
#pragma unroll
    for (int j = 0; j < 8; ++j) acc[j] += __shfl_xor(acc[j], d);
  }
  float inv = 1.f / ws;

  if (lane < 16) {
    u16x8 o;
#pragma unroll
    for (int j = 0; j < 8; ++j) {
      float v = acc[j] * inv + bias[chb + j];
      o[j] = f2bf(v > 0.f ? v : expm1f(v));  // ELU
    }
    *(u16x8*)&outb[(size_t)wid * 256 + chb] = o;
  }
}

// ------------------- layer-2 aggregation (fp8, 16 lanes/edge) --------------
__global__ __launch_bounds__(256) void agg2_kernel(const unsigned char* __restrict__ hq,
                                                   const float* __restrict__ als,
                                                   const float* __restrict__ ald,
                                                   const int* __restrict__ off,
                                                   const int* __restrict__ csr,
                                                   const float* __restrict__ bias,
                                                   float* __restrict__ out, int N) {
  int wid = blockIdx.x * 4 + (threadIdx.x >> 6);
  if (wid >= N) return;
  int lane = threadIdx.x & 63;
  int rs = off[wid], re = off[wid + 1];
  int es = lane >> 4;   // 4 edge streams
  int gl = lane & 15;   // 8 channels each
  int head = gl >> 1;   // 16 ch/head
  float aldv = ald[wid * 8 + head];

  float acc[8];
#pragma unroll
  for (int j = 0; j < 8; ++j) acc[j] = 0.f;
  float ws = 0.f;

  int i = rs + es;
  for (; i + 4 < re; i += 8) {
    int s0 = csr[i], s1 = csr[i + 4];
    float e0 = als[s0 * 8 + head] + aldv;
    float e1 = als[s1 * 8 + head] + aldv;
    uint2 u0 = *(const uint2*)&hq[(size_t)s0 * 128 + gl * 8];
    uint2 u1 = *(const uint2*)&hq[(size_t)s1 * 128 + gl * 8];
    e0 = fmaxf(e0, 0.2f * e0);
    e1 = fmaxf(e1, 0.2f * e1);
    float w0 = __expf(e0), w1 = __expf(e1);
    ws += w0 + w1;
    float d0[8], d1[8];
    fp8dec4(u0.x, d0); fp8dec4(u0.y, d0 + 4);
    fp8dec4(u1.x, d1); fp8dec4(u1.y, d1 + 4);
#pragma unroll
    for (int j = 0; j < 8; ++j)
      acc[j] = fmaf(w1, d1[j], fmaf(w0, d0[j], acc[j]));
  }
  if (i < re) {
    int s0 = csr[i];
    float e0 = als[s0 * 8 + head] + aldv;
    uint2 u0 = *(const uint2*)&hq[(size_t)s0 * 128 + gl * 8];
    e0 = fmaxf(e0, 0.2f * e0);
    float w0 = __expf(e0);
    ws += w0;
    float d0[8];
    fp8dec4(u0.x, d0); fp8dec4(u0.y, d0 + 4);
#pragma unroll
    for (int j = 0; j < 8; ++j) acc[j] = fmaf(w0, d0[j], acc[j]);
  }

#pragma unroll
  for (int d = 16; d < 64; d <<= 1) {
    ws += __shfl_xor(ws, d);
#pragma unroll
    for (int j = 0; j < 8; ++j) acc[j] += __shfl_xor(acc[j], d);
  }
  float inv = 1.f / ws;

  // normalize, mean over heads (gl = 2h + p), log_softmax over 16 channels
#pragma unroll
  for (int j = 0; j < 8; ++j) acc[j] *= inv;
#pragma unroll
  for (int d = 2; d <= 8; d <<= 1)
#pragma unroll
    for (int j = 0; j < 8; ++j) acc[j] += __shfl_xor(acc[j], d);
  int p = gl & 1;
  float v[8];
#pragma unroll
  for (int j = 0; j < 8; ++j) v[j] = acc[j] * 0.125f + bias[p * 8 + j];
  float m = v[0];
#pragma unroll
  for (int j = 1; j < 8; ++j) m = fmaxf(m, v[j]);
  m = fmaxf(m, __shfl_xor(m, 1));
  float se = 0.f;
#pragma unroll
  for (int j = 0; j < 8; ++j) se += __expf(v[j] - m);
  se += __shfl_xor(se, 1);
  float lse = m + logf(se);
  if (lane < 2) {
    *(float4*)&out[(size_t)wid * 16 + p * 8] =
        make_float4(v[0] - lse, v[1] - lse, v[2] - lse, v[3] - lse);
    *(float4*)&out[(size_t)wid * 16 + p * 8 + 4] =
        make_float4(v[4] - lse, v[5] - lse, v[6] - lse, v[7] - lse);
  }
}

// ---------------------------------------------------------------------------

extern "C" void kernel_launch(void* const* d_in, const int* in_sizes, int n_in,
                              void* d_out, int out_size, void* d_ws, size_t ws_size,
                              hipStream_t stream) {
  const float* x = (const float*)d_in[0];
  const void* ei = d_in[1];
  const float* W1 = (const float*)d_in[2];
  const float* as1 = (const float*)d_in[3];
  const float* ad1 = (const float*)d_in[4];
  const float* b1 = (const float*)d_in[5];
  const float* W2 = (const float*)d_in[6];
  const float* as2 = (const float*)d_in[7];
  const float* ad2 = (const float*)d_in[8];
  const float* b2 = (const float*)d_in[9];
  float* out = (float*)d_out;

  const int N = out_size / 16;    // 100000
  const int E = in_sizes[1] / 2;  // 800000
  const int ET = E + N;

  char* p = (char*)d_ws;
  auto alloc = [&](size_t bytes) {
    char* r = p;
    p += (bytes + 255) & ~(size_t)255;
    return (void*)r;
  };
  unsigned char* h1q = (unsigned char*)alloc((size_t)N * 256);  // fp8 L1 rows
  short* hactb = (short*)alloc((size_t)N * 256 * 2);            // ELU out bf16
  float* als = (float*)alloc((size_t)N * 8 * 4);
  float* ald = (float*)alloc((size_t)N * 8 * 4);
  int* src32 = (int*)alloc((size_t)ET * 4);
  int* dst32 = (int*)alloc((size_t)ET * 4);
  int* csr = (int*)alloc((size_t)ET * 4);
  int* deg = (int*)alloc((size_t)N * 4);   // also the fill ticket
  int* flag = (int*)alloc(256);            // adjacent to deg -> merged memset
  int* off = (int*)alloc((size_t)(N + 1) * 4);
  int* bsum = (int*)alloc(256 * 4);
  short* W1p = (short*)alloc(128 * 256 * 2);
  short* W2p = (short*)alloc(256 * 128 * 2);
  unsigned char* h2q = h1q;  // h1q dead after agg1; 128B rows fit

  // deg rounds to a 256B boundary, flag sits right after: one memset
  hipMemsetAsync(deg, 0, (((size_t)N * 4 + 255) & ~(size_t)255) + 4, stream);

  pack2_kernel<<<257, 256, 0, stream>>>(W1, W1p, W2, W2p, (const int*)ei, E, flag);

  int gemmGrid = (N + 63) / 64;
  int gridET = (ET + 255) / 256;
  int nodeGrid = (N + 3) / 4;
  int nscan = (N + 2047) / 2048;

  mega1_kernel<<<gemmGrid + gridET, 256, 0, stream>>>(
      x, W1p, h1q, as1, ad1, als, ald, N, gemmGrid, ei, E, N, flag, src32,
      dst32, deg);
  scan_a<<<nscan, 256, 0, stream>>>(deg, off, bsum, N);
  scan_c<<<(N + 256) / 256, 256, 0, stream>>>(off, bsum, N, nscan);
  fill_kernel<<<gridET, 256, 0, stream>>>(src32, dst32, off, deg, csr, ET);

  agg1_kernel<<<dim3(nodeGrid, 2), 256, 0, stream>>>(h1q, als, ald, off, csr,
                                                     b1, hactb, N);
  mfma_gemm<256, 128, false><<<gemmGrid, 256, 0, stream>>>(
      hactb, W2p, h2q, as2, ad2, als, ald, N);
  agg2_kernel<<<nodeGrid, 256, 0, stream>>>(h2q, als, ald, off, csr, b2, out, N);
}

// Round 13
// 320.794 us; speedup vs baseline: 1.1654x; 1.1654x over previous
//
#include <hip/hip_runtime.h>
#include <cstdint>
#include <cstddef>

// ---------------------------------------------------------------------------
// 2-layer GAT on MI355X — fp8 value rows both layers, fused dispatch graph,
// 4-deep unrolled agg1 gather loop (latency hiding).  [= round-11 best]
//   memset(deg+flag) ; pack2(W1+W2 + detect block)
//   mega1: [gemm1: h1q(fp8)=x@W1 + fused als/ald] || [extract blocks]
//   scan_a ; scan_c(inline bsum scan) ; fill
//   agg1 (fp8 256B rows, 32 lanes/edge, 2 streams, 4x unroll) -> hactb bf16
//   gemm2: h2q(fp8 128B rows) = hactb @ W2 + fused als/ald
//   agg2 (fp8 128B = 1 line/row, 16 lanes/edge, 4 streams) -> log_softmax out
//
// Perf model (closed, rounds 2-12): agg kernels are at the random-line
// service floor — FETCH = working_set x XCD-spread (25.6MB x 5.6 = 145MB,
// measured), served at ~2.3 TB/s; uniform-random graph => no locality.
// ---------------------------------------------------------------------------

typedef short bf16x8 __attribute__((ext_vector_type(8)));
typedef unsigned short u16x8 __attribute__((ext_vector_type(8)));
typedef float f32x4 __attribute__((ext_vector_type(4)));

__device__ inline unsigned short f2bf(float f) {
  unsigned u = __float_as_uint(f);
  unsigned r = (u + 0x7FFFu + ((u >> 16) & 1u)) >> 16;  // RNE
  return (unsigned short)r;
}
__device__ inline float bf2f(unsigned short s) {
  return __uint_as_float((unsigned)s << 16);
}

// ---- OCP e4m3fn helpers ---------------------------------------------------
__device__ inline unsigned char fp8enc(float x) {
  unsigned u = __float_as_uint(x);
  unsigned s = u >> 31;
  float ax = fminf(fabsf(x), 448.f);
  unsigned em;
  if (ax >= 0.015625f) {  // normal
    unsigned b = __float_as_uint(ax);
    unsigned b2 = b + 0x7FFFFu + ((b >> 20) & 1u);  // RNE to 3 mantissa bits
    em = (b2 >> 20) - 960u;
    if (em > 126u) em = 126u;  // clamp to 448
  } else {                     // denormal: m * 2^-9
    em = (unsigned)__float2int_rn(ax * 512.f);
  }
  return (unsigned char)((s << 7) | em);
}
__device__ inline float fp8dec_sw(unsigned b8) {
  unsigned s = b8 >> 7, em = b8 & 0x7Fu;
  float fn = __uint_as_float((s << 31) | ((em + 960u) << 20));
  float fd = (float)em * 0.001953125f;
  fd = s ? -fd : fd;
  return em >= 8u ? fn : fd;
}
__device__ inline void fp8dec4(unsigned w, float* out) {
#if __has_builtin(__builtin_amdgcn_cvt_f32_fp8)
  out[0] = __builtin_amdgcn_cvt_f32_fp8(w, 0);
  out[1] = __builtin_amdgcn_cvt_f32_fp8(w, 1);
  out[2] = __builtin_amdgcn_cvt_f32_fp8(w, 2);
  out[3] = __builtin_amdgcn_cvt_f32_fp8(w, 3);
#else
  out[0] = fp8dec_sw(w & 0xFFu);
  out[1] = fp8dec_sw((w >> 8) & 0xFFu);
  out[2] = fp8dec_sw((w >> 16) & 0xFFu);
  out[3] = fp8dec_sw((w >> 24) & 0xFFu);
#endif
}

// ------------------------------- CSR build ---------------------------------

__global__ __launch_bounds__(256) void scan_a(const int* __restrict__ deg,
                                              int* __restrict__ off,
                                              int* __restrict__ bsum, int N) {
  __shared__ int sh[256];
  int b = blockIdx.x, t = threadIdx.x;
  int base = b * 2048 + t * 8;
  int p[8];
  int run = 0;
#pragma unroll
  for (int j = 0; j < 8; ++j) {
    int v = (base + j < N) ? deg[base + j] : 0;
    run += v;
    p[j] = run;
  }
  sh[t] = run;
  __syncthreads();
  for (int d = 1; d < 256; d <<= 1) {
    int x = (t >= d) ? sh[t - d] : 0;
    __syncthreads();
    if (t >= d) sh[t] += x;
    __syncthreads();
  }
  int excl = sh[t] - run;
#pragma unroll
  for (int j = 0; j < 8; ++j)
    if (base + j < N) off[base + j + 1] = excl + p[j];
  if (t == 255) bsum[b] = sh[255];
}

// scan_c with inlined bsum scan; nb <= 64
__global__ __launch_bounds__(256) void scan_c(int* __restrict__ off,
                                              const int* __restrict__ bsum,
                                              int N, int nb) {
  __shared__ int sb[64];
  int t = threadIdx.x;
  if (t < 64) {
    int v = (t < nb) ? bsum[t] : 0;
    for (int d = 1; d < 64; d <<= 1) {
      int u = __shfl_up(v, d);
      if (t >= d) v += u;
    }
    sb[t] = v;  // inclusive scan
  }
  __syncthreads();
  int i = blockIdx.x * 256 + t;
  if (i == 0) off[0] = 0;
  if (i >= 1 && i <= N) {
    int c = (i - 1) / 2048;
    int excl = (c == 0) ? 0 : sb[c - 1];
    off[i] += excl;
  }
}

__global__ __launch_bounds__(256) void fill_kernel(const int* __restrict__ src,
                                                   const int* __restrict__ dst,
                                                   const int* __restrict__ off,
                                                   int* __restrict__ deg,
                                                   int* __restrict__ csr, int ET) {
  int e = blockIdx.x * 256 + threadIdx.x;
  if (e >= ET) return;
  int d = dst[e];
  int p = atomicSub(&deg[d], 1) - 1;
  csr[off[d] + p] = src[e];
}

// ------------------- weight pre-pack + int-width detect --------------------
__device__ inline void pack_one(const float* __restrict__ W,
                                short* __restrict__ Wp, int NOUT, int idx) {
  int NT = NOUT >> 4;
  int j = idx & 7;
  int lane = (idx >> 3) & 63;
  int st = idx >> 9;
  int s = st / NT, t = st - s * NT;
  int k = s * 32 + (lane >> 4) * 8 + j;
  int n = t * 16 + (lane & 15);
  Wp[idx] = (short)f2bf(W[(size_t)k * NOUT + n]);
}

__global__ __launch_bounds__(256) void pack2_kernel(const float* __restrict__ W1,
                                                    short* __restrict__ W1p,
                                                    const float* __restrict__ W2,
                                                    short* __restrict__ W2p,
                                                    const int* __restrict__ words,
                                                    int E, int* __restrict__ flag) {
  int b = blockIdx.x, t = threadIdx.x;
  if (b < 128) {
    pack_one(W1, W1p, 256, b * 256 + t);          // 128*256 elems
  } else if (b < 256) {
    pack_one(W2, W2p, 128, (b - 128) * 256 + t);  // 256*128 elems
  } else {                                        // detect block
    int n = E < 1024 ? E : 1024;
    int cnt = 0;
    for (int i = t; i < n; i += 256) cnt += (words[2 * i + 1] != 0) ? 1 : 0;
    for (int m = 1; m < 64; m <<= 1) cnt += __shfl_xor(cnt, m);
    if ((t & 63) == 0 && cnt) atomicAdd(flag, cnt);
  }
}

// ------------------------------ MFMA GEMM body -----------------------------
template <int K, int NOUT, bool AF32>
__device__ void gemm_body(int bx, const void* __restrict__ Av,
                          const short* __restrict__ Bp,
                          unsigned char* __restrict__ Cq,
                          const float* __restrict__ as,
                          const float* __restrict__ ad,
                          float* __restrict__ alsO,
                          float* __restrict__ aldO, int M) {
  constexpr int KS = K / 32;
  constexpr int NT = NOUT / 16;
  constexpr int RST = NOUT + 8;   // bf16 LDS row stride (shorts)
  constexpr int QST = NOUT + 16;  // fp8 LDS row stride (bytes)
  constexpr int C = NOUT / 8;     // channels per head
  __shared__ __align__(16) short lds[64 * RST];
  __shared__ __align__(16) unsigned char ldsq[64 * QST];
  const int tid = threadIdx.x;
  const int wave = tid >> 6, lane = tid & 63;
  const int lo = lane & 15, hi = lane >> 4;
  const int rowA = bx * 64 + wave * 16 + lo;
  const bool inb = rowA < M;

  f32x4 acc[NT];
#pragma unroll
  for (int t = 0; t < NT; ++t) acc[t] = (f32x4){0.f, 0.f, 0.f, 0.f};

#pragma unroll
  for (int s = 0; s < KS; ++s) {
    bf16x8 af;
    if constexpr (AF32) {
      const float* Ap = (const float*)Av;
      float v[8];
      if (inb) {
        const float4 x0 = *(const float4*)&Ap[(size_t)rowA * K + s * 32 + hi * 8];
        const float4 x1 = *(const float4*)&Ap[(size_t)rowA * K + s * 32 + hi * 8 + 4];
        v[0] = x0.x; v[1] = x0.y; v[2] = x0.z; v[3] = x0.w;
        v[4] = x1.x; v[5] = x1.y; v[6] = x1.z; v[7] = x1.w;
      } else {
#pragma unroll
        for (int j = 0; j < 8; ++j) v[j] = 0.f;
      }
#pragma unroll
      for (int j = 0; j < 8; ++j) af[j] = (short)f2bf(v[j]);
    } else {
      const short* Ab = (const short*)Av;
      if (inb) {
        af = *(const bf16x8*)&Ab[(size_t)rowA * K + s * 32 + hi * 8];
      } else {
#pragma unroll
        for (int j = 0; j < 8; ++j) af[j] = 0;
      }
    }
#pragma unroll
    for (int t = 0; t < NT; ++t) {
      bf16x8 bf = *(const bf16x8*)&Bp[((size_t)(s * NT + t) * 64 + lane) * 8];
      acc[t] = __builtin_amdgcn_mfma_f32_16x16x32_bf16(af, bf, acc[t], 0, 0, 0);
    }
  }

#pragma unroll
  for (int t = 0; t < NT; ++t)
#pragma unroll
    for (int r = 0; r < 4; ++r) {
      int row = wave * 16 + hi * 4 + r;
      lds[row * RST + t * 16 + lo] = (short)f2bf(acc[t][r]);
      ldsq[row * QST + t * 16 + lo] = fp8enc(acc[t][r]);
    }
  __syncthreads();

  // coalesced fp8 store
  constexpr int CPR = NOUT / 16;  // 16B chunks per row
#pragma unroll
  for (int i = 0; i < (64 * CPR) / 256; ++i) {
    int v = i * 256 + tid;
    int r = v / CPR;
    int c = v % CPR;
    int grow = bx * 64 + r;
    if (grow < M)
      *(float4*)&Cq[(size_t)grow * NOUT + c * 16] =
          *(const float4*)&ldsq[r * QST + c * 16];
  }

  // fused al epilogue (bf16 LDS tile — logits stay full precision)
  constexpr int SEGS = NOUT / 64;
  if (tid < 64 * SEGS) {
    int r = tid / SEGS, seg = tid % SEGS;
    int grow = bx * 64 + r;
    float ps[8], pd[8];
#pragma unroll
    for (int k = 0; k < 8; ++k) { ps[k] = 0.f; pd[k] = 0.f; }
#pragma unroll
    for (int k = 0; k < 8; ++k) {
      int b = seg + SEGS * k;
      u16x8 u = *(const u16x8*)&lds[r * RST + b * 8];
#pragma unroll
      for (int j = 0; j < 8; ++j) {
        float hv = bf2f(u[j]);
        ps[k] = fmaf(hv, as[k * C + seg * 8 + j], ps[k]);
        pd[k] = fmaf(hv, ad[k * C + seg * 8 + j], pd[k]);
      }
    }
#pragma unroll
    for (int d = 1; d < SEGS; d <<= 1)
#pragma unroll
      for (int k = 0; k < 8; ++k) {
        ps[k] += __shfl_xor(ps[k], d);
        pd[k] += __shfl_xor(pd[k], d);
      }
    if (seg == 0 && grow < M) {
      *(float4*)&alsO[(size_t)grow * 8] = make_float4(ps[0], ps[1], ps[2], ps[3]);
      *(float4*)&alsO[(size_t)grow * 8 + 4] = make_float4(ps[4], ps[5], ps[6], ps[7]);
      *(float4*)&aldO[(size_t)grow * 8] = make_float4(pd[0], pd[1], pd[2], pd[3]);
      *(float4*)&aldO[(size_t)grow * 8 + 4] = make_float4(pd[4], pd[5], pd[6], pd[7]);
    }
  }
}

// mega1: gemm1 blocks || extract blocks
__global__ __launch_bounds__(256) void mega1_kernel(
    const float* __restrict__ x, const short* __restrict__ W1p,
    unsigned char* __restrict__ h1q, const float* __restrict__ as1,
    const float* __restrict__ ad1, float* __restrict__ als,
    float* __restrict__ ald, int M, int gemmGrid,
    const void* __restrict__ ei, int E, int N, const int* __restrict__ flag,
    int* __restrict__ src, int* __restrict__ dst, int* __restrict__ deg) {
  int bx = blockIdx.x;
  if (bx < gemmGrid) {
    gemm_body<128, 256, true>(bx, x, W1p, h1q, as1, ad1, als, ald, M);
  } else {
    int e = (bx - gemmGrid) * 256 + threadIdx.x;
    int ET = E + N;
    if (e >= ET) return;
    int s, d;
    if (e < E) {
      if (flag[0] == 0) {  // int64
        const long long* p = (const long long*)ei;
        s = (int)p[e];
        d = (int)p[(size_t)E + e];
      } else {             // int32
        const int* p = (const int*)ei;
        s = p[e];
        d = p[E + e];
      }
    } else {
      s = d = e - E;  // self loop
    }
    src[e] = s;
    dst[e] = d;
    atomicAdd(&deg[d], 1);
  }
}

template <int K, int NOUT, bool AF32>
__global__ __launch_bounds__(256) void mfma_gemm(const void* __restrict__ Av,
                                                 const short* __restrict__ Bp,
                                                 unsigned char* __restrict__ Cq,
                                                 const float* __restrict__ as,
                                                 const float* __restrict__ ad,
                                                 float* __restrict__ alsO,
                                                 float* __restrict__ aldO, int M) {
  gemm_body<K, NOUT, AF32>(blockIdx.x, Av, Bp, Cq, as, ad, alsO, aldO, M);
}

// ------------------- layer-1 aggregation (fp8, 4-deep unroll) --------------
// 32 lanes/edge x uint2, 2 streams. Main loop: 4 edges/stream-iteration
// (all 4 csr+als+row loads issue before the first dependent use).
__global__ __launch_bounds__(256) void agg1_kernel(const unsigned char* __restrict__ hq,
                                                   const float* __restrict__ als,
                                                   const float* __restrict__ ald,
                                                   const int* __restrict__ off,
                                                   const int* __restrict__ csr,
                                                   const float* __restrict__ bias,
                                                   short* __restrict__ outb, int N) {
  int wid = blockIdx.x * 4 + (threadIdx.x >> 6);
  if (wid >= N) return;
  int lane = threadIdx.x & 63;
  int rs = off[wid], re = off[wid + 1];
  int es = lane >> 5;       // 2 edge streams
  int gl = lane & 31;       // 8 channels each
  int head = gl >> 2;
  float aldv = ald[wid * 8 + head];

  float acc[8];
#pragma unroll
  for (int j = 0; j < 8; ++j) acc[j] = 0.f;
  float ws = 0.f;

  int i = rs + es;
  // main: 4 edges per iteration
  for (; i + 6 < re; i += 8) {
    int s0 = csr[i], s1 = csr[i + 2], s2 = csr[i + 4], s3 = csr[i + 6];
    float a0 = als[s0 * 8 + head];
    float a1 = als[s1 * 8 + head];
    float a2 = als[s2 * 8 + head];
    float a3 = als[s3 * 8 + head];
    uint2 u0 = *(const uint2*)&hq[(size_t)s0 * 256 + gl * 8];
    uint2 u1 = *(const uint2*)&hq[(size_t)s1 * 256 + gl * 8];
    uint2 u2 = *(const uint2*)&hq[(size_t)s2 * 256 + gl * 8];
    uint2 u3 = *(const uint2*)&hq[(size_t)s3 * 256 + gl * 8];
    float e0 = a0 + aldv, e1 = a1 + aldv, e2 = a2 + aldv, e3 = a3 + aldv;
    e0 = fmaxf(e0, 0.2f * e0); e1 = fmaxf(e1, 0.2f * e1);
    e2 = fmaxf(e2, 0.2f * e2); e3 = fmaxf(e3, 0.2f * e3);
    float w0 = __expf(e0), w1 = __expf(e1), w2 = __expf(e2), w3 = __expf(e3);
    ws += (w0 + w1) + (w2 + w3);
    float da[4], db[4];
    fp8dec4(u0.x, da); fp8dec4(u0.y, db);
#pragma unroll
    for (int j = 0; j < 4; ++j) {
      acc[j] = fmaf(w0, da[j], acc[j]);
      acc[j + 4] = fmaf(w0, db[j], acc[j + 4]);
    }
    fp8dec4(u1.x, da); fp8dec4(u1.y, db);
#pragma unroll
    for (int j = 0; j < 4; ++j) {
      acc[j] = fmaf(w1, da[j], acc[j]);
      acc[j + 4] = fmaf(w1, db[j], acc[j + 4]);
    }
    fp8dec4(u2.x, da); fp8dec4(u2.y, db);
#pragma unroll
    for (int j = 0; j < 4; ++j) {
      acc[j] = fmaf(w2, da[j], acc[j]);
      acc[j + 4] = fmaf(w2, db[j], acc[j + 4]);
    }
    fp8dec4(u3.x, da); fp8dec4(u3.y, db);
#pragma unroll
    for (int j = 0; j < 4; ++j) {
      acc[j] = fmaf(w3, da[j], acc[j]);
      acc[j + 4] = fmaf(w3, db[j], acc[j + 4]);
    }
  }
  // mid: 2 edges
  for (; i + 2 < re; i += 4) {
    int s0 = csr[i], s1 = csr[i + 2];
    float a0 = als[s0 * 8 + head];
    float a1 = als[s1 * 8 + head];
    uint2 u0 = *(const uint2*)&hq[(size_t)s0 * 256 + gl * 8];
    uint2 u1 = *(const uint2*)&hq[(size_t)s1 * 256 + gl * 8];
    float e0 = a0 + aldv, e1 = a1 + aldv;
    e0 = fmaxf(e0, 0.2f * e0);
    e1 = fmaxf(e1, 0.2f * e1);
    float w0 = __expf(e0), w1 = __expf(e1);
    ws += w0 + w1;
    float d0a[4], d0b[4], d1a[4], d1b[4];
    fp8dec4(u0.x, d0a); fp8dec4(u0.y, d0b);
    fp8dec4(u1.x, d1a); fp8dec4(u1.y, d1b);
#pragma unroll
    for (int j = 0; j < 4; ++j) {
      acc[j] = fmaf(w0, d0a[j], acc[j]);
      acc[j + 4] = fmaf(w0, d0b[j], acc[j + 4]);
      acc[j] = fmaf(w1, d1a[j], acc[j]);
      acc[j + 4] = fmaf(w1, d1b[j], acc[j + 4]);
    }
  }
  // tail: 1 edge
  if (i < re) {
    int s0 = csr[i];
    float e0 = als[s0 * 8 + head] + aldv;
    uint2 u0 = *(const uint2*)&hq[(size_t)s0 * 256 + gl * 8];
    e0 = fmaxf(e0, 0.2f * e0);
    float w0 = __expf(e0);
    ws += w0;
    float d0a[4], d0b[4];
    fp8dec4(u0.x, d0a); fp8dec4(u0.y, d0b);
#pragma unroll
    for (int j = 0; j < 4; ++j) {
      acc[j] = fmaf(w0, d0a[j], acc[j]);
      acc[j + 4] = fmaf(w0, d0b[j], acc[j + 4]);
    }
  }

  ws += __shfl_xor(ws, 32);
#pragma unroll
  for (int j = 0; j < 8; ++j) acc[j] += __shfl_xor(acc[j], 32);
  float inv = 1.f / ws;

  if (lane < 32) {
    u16x8 o;
#pragma unroll
    for (int j = 0; j < 8; ++j) {
      float v = acc[j] * inv + bias[gl * 8 + j];
      o[j] = f2bf(v > 0.f ? v : expm1f(v));  // ELU
    }
    *(u16x8*)&outb[(size_t)wid * 256 + gl * 8] = o;
  }
}

// ------------------- layer-2 aggregation (fp8, 16 lanes/edge) --------------
__global__ __launch_bounds__(256) void agg2_kernel(const unsigned char* __restrict__ hq,
                                                   const float* __restrict__ als,
                                                   const float* __restrict__ ald,
                                                   const int* __restrict__ off,
                                                   const int* __restrict__ csr,
                                                   const float* __restrict__ bias,
                                                   float* __restrict__ out, int N) {
  int wid = blockIdx.x * 4 + (threadIdx.x >> 6);
  if (wid >= N) return;
  int lane = threadIdx.x & 63;
  int rs = off[wid], re = off[wid + 1];
  int es = lane >> 4;   // 4 edge streams
  int gl = lane & 15;   // 8 channels each
  int head = gl >> 1;   // 16 ch/head
  float aldv = ald[wid * 8 + head];

  float acc[8];
#pragma unroll
  for (int j = 0; j < 8; ++j) acc[j] = 0.f;
  float ws = 0.f;

  int i = rs + es;
  for (; i + 4 < re; i += 8) {
    int s0 = csr[i], s1 = csr[i + 4];
    float e0 = als[s0 * 8 + head] + aldv;
    float e1 = als[s1 * 8 + head] + aldv;
    uint2 u0 = *(const uint2*)&hq[(size_t)s0 * 128 + gl * 8];
    uint2 u1 = *(const uint2*)&hq[(size_t)s1 * 128 + gl * 8];
    e0 = fmaxf(e0, 0.2f * e0);
    e1 = fmaxf(e1, 0.2f * e1);
    float w0 = __expf(e0), w1 = __expf(e1);
    ws += w0 + w1;
    float d0[8], d1[8];
    fp8dec4(u0.x, d0); fp8dec4(u0.y, d0 + 4);
    fp8dec4(u1.x, d1); fp8dec4(u1.y, d1 + 4);
#pragma unroll
    for (int j = 0; j < 8; ++j)
      acc[j] = fmaf(w1, d1[j], fmaf(w0, d0[j], acc[j]));
  }
  if (i < re) {
    int s0 = csr[i];
    float e0 = als[s0 * 8 + head] + aldv;
    uint2 u0 = *(const uint2*)&hq[(size_t)s0 * 128 + gl * 8];
    e0 = fmaxf(e0, 0.2f * e0);
    float w0 = __expf(e0);
    ws += w0;
    float d0[8];
    fp8dec4(u0.x, d0); fp8dec4(u0.y, d0 + 4);
#pragma unroll
    for (int j = 0; j < 8; ++j) acc[j] = fmaf(w0, d0[j], acc[j]);
  }

#pragma unroll
  for (int d = 16; d < 64; d <<= 1) {
    ws += __shfl_xor(ws, d);
#pragma unroll
    for (int j = 0; j < 8; ++j) acc[j] += __shfl_xor(acc[j], d);
  }
  float inv = 1.f / ws;

  // normalize, mean over heads (gl = 2h + p), log_softmax over 16 channels
#pragma unroll
  for (int j = 0; j < 8; ++j) acc[j] *= inv;
#pragma unroll
  for (int d = 2; d <= 8; d <<= 1)
#pragma unroll
    for (int j = 0; j < 8; ++j) acc[j] += __shfl_xor(acc[j], d);
  int p = gl & 1;
  float v[8];
#pragma unroll
  for (int j = 0; j < 8; ++j) v[j] = acc[j] * 0.125f + bias[p * 8 + j];
  float m = v[0];
#pragma unroll
  for (int j = 1; j < 8; ++j) m = fmaxf(m, v[j]);
  m = fmaxf(m, __shfl_xor(m, 1));
  float se = 0.f;
#pragma unroll
  for (int j = 0; j < 8; ++j) se += __expf(v[j] - m);
  se += __shfl_xor(se, 1);
  float lse = m + logf(se);
  if (lane < 2) {
    *(float4*)&out[(size_t)wid * 16 + p * 8] =
        make_float4(v[0] - lse, v[1] - lse, v[2] - lse, v[3] - lse);
    *(float4*)&out[(size_t)wid * 16 + p * 8 + 4] =
        make_float4(v[4] - lse, v[5] - lse, v[6] - lse, v[7] - lse);
  }
}

// ---------------------------------------------------------------------------

extern "C" void kernel_launch(void* const* d_in, const int* in_sizes, int n_in,
                              void* d_out, int out_size, void* d_ws, size_t ws_size,
                              hipStream_t stream) {
  const float* x = (const float*)d_in[0];
  const void* ei = d_in[1];
  const float* W1 = (const float*)d_in[2];
  const float* as1 = (const float*)d_in[3];
  const float* ad1 = (const float*)d_in[4];
  const float* b1 = (const float*)d_in[5];
  const float* W2 = (const float*)d_in[6];
  const float* as2 = (const float*)d_in[7];
  const float* ad2 = (const float*)d_in[8];
  const float* b2 = (const float*)d_in[9];
  float* out = (float*)d_out;

  const int N = out_size / 16;    // 100000
  const int E = in_sizes[1] / 2;  // 800000
  const int ET = E + N;

  char* p = (char*)d_ws;
  auto alloc = [&](size_t bytes) {
    char* r = p;
    p += (bytes + 255) & ~(size_t)255;
    return (void*)r;
  };
  unsigned char* h1q = (unsigned char*)alloc((size_t)N * 256);  // fp8 L1 rows
  short* hactb = (short*)alloc((size_t)N * 256 * 2);            // ELU out bf16
  float* als = (float*)alloc((size_t)N * 8 * 4);
  float* ald = (float*)alloc((size_t)N * 8 * 4);
  int* src32 = (int*)alloc((size_t)ET * 4);
  int* dst32 = (int*)alloc((size_t)ET * 4);
  int* csr = (int*)alloc((size_t)ET * 4);
  int* deg = (int*)alloc((size_t)N * 4);   // also the fill ticket
  int* flag = (int*)alloc(256);            // adjacent to deg -> merged memset
  int* off = (int*)alloc((size_t)(N + 1) * 4);
  int* bsum = (int*)alloc(256 * 4);
  short* W1p = (short*)alloc(128 * 256 * 2);
  short* W2p = (short*)alloc(256 * 128 * 2);
  unsigned char* h2q = h1q;  // h1q dead after agg1; 128B rows fit

  // deg rounds to a 256B boundary, flag sits right after: one memset
  hipMemsetAsync(deg, 0, (((size_t)N * 4 + 255) & ~(size_t)255) + 4, stream);

  pack2_kernel<<<257, 256, 0, stream>>>(W1, W1p, W2, W2p, (const int*)ei, E, flag);

  int gemmGrid = (N + 63) / 64;
  int gridET = (ET + 255) / 256;
  int nodeGrid = (N + 3) / 4;
  int nscan = (N + 2047) / 2048;

  mega1_kernel<<<gemmGrid + gridET, 256, 0, stream>>>(
      x, W1p, h1q, as1, ad1, als, ald, N, gemmGrid, ei, E, N, flag, src32,
      dst32, deg);
  scan_a<<<nscan, 256, 0, stream>>>(deg, off, bsum, N);
  scan_c<<<(N + 256) / 256, 256, 0, stream>>>(off, bsum, N, nscan);
  fill_kernel<<<gridET, 256, 0, stream>>>(src32, dst32, off, deg, csr, ET);

  agg1_kernel<<<nodeGrid, 256, 0, stream>>>(h1q, als, ald, off, csr, b1, hactb, N);
  mfma_gemm<256, 128, false><<<gemmGrid, 256, 0, stream>>>(
      hactb, W2p, h2q, as2, ad2, als, ald, N);
  agg2_kernel<<<nodeGrid, 256, 0, stream>>>(h2q, als, ald, off, csr, b2, out, N);
}